// Round 7
// baseline (1889.060 us; speedup 1.0000x reference)
//
#include <hip/hip_runtime.h>

// ---------------------------------------------------------------------------
// Swin block, MI355X. ALL I/O fp32 (per reference); bf16 MFMA compute inside,
// fp32 accumulate + fp32 residual chain.
// ZERO-workspace: d_ws never touched; d_out (fp32, 77 MB) is the only buffer.
//   K1: x -> attn_out (pixel order, bijective scatter)          [d_out]
//   K2: attn_out -> xr = proj(attn)+x, in-place row-local       [d_out]
//   K3: xr -> xr + fc2(gelu(fc1(ln2(xr)))), in-place row-local  [d_out]
// B=64 H=W=28 DIM=384 HEADS=12 HD=32 WIN=7 SHIFT=3 N=49 NW=16 HID=1536
// tokens = 50176, windows = 1024.
// ---------------------------------------------------------------------------

using u16 = unsigned short;
typedef __bf16 bf16x8 __attribute__((ext_vector_type(8)));
typedef float  f32x4  __attribute__((ext_vector_type(4)));

__device__ __forceinline__ float bf2f(u16 u) {
  unsigned x = ((unsigned)u) << 16; return __builtin_bit_cast(float, x);
}
__device__ __forceinline__ u16 f2bf(float f) {
  unsigned x = __builtin_bit_cast(unsigned, f);
  x += 0x7fffu + ((x >> 16) & 1u);   // RNE
  return (u16)(x >> 16);
}
__device__ __forceinline__ int region3(int s) { return s < 21 ? 0 : (s < 25 ? 1 : 2); }
__device__ __forceinline__ void unpack8(uint4 u, float* d) {
  d[0] = bf2f(u.x & 0xffff); d[1] = bf2f(u.x >> 16);
  d[2] = bf2f(u.y & 0xffff); d[3] = bf2f(u.y >> 16);
  d[4] = bf2f(u.z & 0xffff); d[5] = bf2f(u.z >> 16);
  d[6] = bf2f(u.w & 0xffff); d[7] = bf2f(u.w >> 16);
}
// 8 consecutive fp32 -> packed 8x bf16 (uint4)
__device__ __forceinline__ uint4 pack8f(const float* p) {
  float4 a = *(const float4*)p, b = *(const float4*)(p + 4);
  uint4 u;
  u.x = (unsigned)f2bf(a.x) | ((unsigned)f2bf(a.y) << 16);
  u.y = (unsigned)f2bf(a.z) | ((unsigned)f2bf(a.w) << 16);
  u.z = (unsigned)f2bf(b.x) | ((unsigned)f2bf(b.y) << 16);
  u.w = (unsigned)f2bf(b.z) | ((unsigned)f2bf(b.w) << 16);
  return u;
}
// 8 consecutive fp32 -> bf16x8 MFMA fragment
__device__ __forceinline__ bf16x8 ldw8(const float* p) {
  float4 a = *(const float4*)p, b = *(const float4*)(p + 4);
  bf16x8 r;
  r[0] = __builtin_bit_cast(__bf16, f2bf(a.x));
  r[1] = __builtin_bit_cast(__bf16, f2bf(a.y));
  r[2] = __builtin_bit_cast(__bf16, f2bf(a.z));
  r[3] = __builtin_bit_cast(__bf16, f2bf(a.w));
  r[4] = __builtin_bit_cast(__bf16, f2bf(b.x));
  r[5] = __builtin_bit_cast(__bf16, f2bf(b.y));
  r[6] = __builtin_bit_cast(__bf16, f2bf(b.z));
  r[7] = __builtin_bit_cast(__bf16, f2bf(b.w));
  return r;
}

// ---------------------------------------------------------------------------
// K1: per-window fused LN1 + QKV + attention. One block per window (1024).
// xin[64][392] bf16 (rows 49-63 zeroed), qkvs[49][192] bf16.
// Scatter attn_out (fp32) to final pixel positions (bijective, race-free).
// ---------------------------------------------------------------------------
__global__ __launch_bounds__(256) void win_attn_kernel(
    const float* __restrict__ x, const float* __restrict__ n1w, const float* __restrict__ n1b,
    const float* __restrict__ qkv_w, const float* __restrict__ qkv_b,
    const float* __restrict__ btab, float* __restrict__ out)
{
  __shared__ __align__(16) u16 xin[64 * 392];    // 50,176 B
  __shared__ __align__(16) u16 qkvs[49 * 192];   // 18,816 B
  __shared__ float mustd[98];

  const int tid  = threadIdx.x;
  const int lane = tid & 63;
  const int wave = tid >> 6;
  const int quad = lane >> 4;
  const int r16  = lane & 15;

  const int win  = blockIdx.x;
  const int bimg = win >> 4;
  const int wi   = win & 15;
  const int wwh  = wi >> 2, www = wi & 3;

  // zero pad rows 49..63 (read by MFMA A-tiles)
  for (int e = tid * 8; e < 15 * 392; e += 2048)
    *(uint4*)&xin[49 * 392 + e] = make_uint4(0, 0, 0, 0);

  // stage shifted window rows from x (fp32 -> bf16)
  for (int e = tid * 8; e < 49 * 384; e += 2048) {
    int r = e / 384, c = e - (e / 384) * 384;
    int i = r / 7, j = r - (r / 7) * 7;
    int h  = wwh * 7 + i + 3; if (h  >= 28) h  -= 28;
    int w2 = www * 7 + j + 3; if (w2 >= 28) w2 -= 28;
    *(uint4*)&xin[r * 392 + c] =
        pack8f(x + ((size_t)(bimg * 784 + h * 28 + w2)) * 384 + c);
  }
  __syncthreads();

  // LN1 stats (one wave per row)
  for (int r = wave; r < 49; r += 4) {
    float v[6]; float s = 0.f;
#pragma unroll
    for (int k = 0; k < 6; ++k) { v[k] = bf2f(xin[r * 392 + lane + k * 64]); s += v[k]; }
#pragma unroll
    for (int off = 32; off; off >>= 1) s += __shfl_xor(s, off);
    float mu = s * (1.f / 384.f);
    float vs = 0.f;
#pragma unroll
    for (int k = 0; k < 6; ++k) { float d = v[k] - mu; vs += d * d; }
#pragma unroll
    for (int off = 32; off; off >>= 1) vs += __shfl_xor(vs, off);
    if (lane == 0) { mustd[r] = mu; mustd[49 + r] = rsqrtf(vs * (1.f / 384.f) + 1e-5f); }
  }
  __syncthreads();

  // normalize rows 0..48 in place (weights fp32)
  for (int e = tid * 8; e < 49 * 384; e += 2048) {
    int r = e / 384, c = e - (e / 384) * 384;
    float mu = mustd[r], rs = mustd[49 + r];
    float v[8];
    unpack8(*(uint4*)&xin[r * 392 + c], v);
    float4 w0 = *(const float4*)(n1w + c), w1 = *(const float4*)(n1w + c + 4);
    float4 b0 = *(const float4*)(n1b + c), b1 = *(const float4*)(n1b + c + 4);
    float wv[8] = {w0.x, w0.y, w0.z, w0.w, w1.x, w1.y, w1.z, w1.w};
    float bv[8] = {b0.x, b0.y, b0.z, b0.w, b1.x, b1.y, b1.z, b1.w};
    unsigned pk[4];
#pragma unroll
    for (int i = 0; i < 4; ++i) {
      u16 a = f2bf((v[2*i]   - mu) * rs * wv[2*i]   + bv[2*i]);
      u16 b = f2bf((v[2*i+1] - mu) * rs * wv[2*i+1] + bv[2*i+1]);
      pk[i] = (unsigned)a | ((unsigned)b << 16);
    }
    *(uint4*)&xin[r * 392 + c] = make_uint4(pk[0], pk[1], pk[2], pk[3]);
  }
  __syncthreads();

  // per head-pair: QKV slice (N=192) then attention for 2 heads
  for (int hp = 0; hp < 6; ++hp) {
    f32x4 acc[4][3];
#pragma unroll
    for (int a = 0; a < 4; ++a)
#pragma unroll
      for (int c = 0; c < 3; ++c) acc[a][c] = (f32x4){0.f, 0.f, 0.f, 0.f};

    for (int k0 = 0; k0 < 384; k0 += 32) {
      bf16x8 af[4];
#pragma unroll
      for (int mt = 0; mt < 4; ++mt)
        af[mt] = *(const bf16x8*)&xin[(mt * 16 + r16) * 392 + k0 + quad * 8];
#pragma unroll
      for (int nt = 0; nt < 3; ++nt) {
        int n = wave * 48 + nt * 16 + r16;
        int f = (n >> 6) * 384 + hp * 64 + (n & 63);
        bf16x8 bf = ldw8(qkv_w + (size_t)f * 384 + k0 + quad * 8);
#pragma unroll
        for (int mt = 0; mt < 4; ++mt)
          acc[mt][nt] = __builtin_amdgcn_mfma_f32_16x16x32_bf16(af[mt], bf, acc[mt][nt], 0, 0, 0);
      }
    }
#pragma unroll
    for (int mt = 0; mt < 4; ++mt) {
#pragma unroll
      for (int nt = 0; nt < 3; ++nt) {
#pragma unroll
        for (int rg = 0; rg < 4; ++rg) {
          int row = mt * 16 + quad * 4 + rg;
          if (row < 49) {
            int n = wave * 48 + nt * 16 + r16;
            int f = (n >> 6) * 384 + hp * 64 + (n & 63);
            qkvs[row * 192 + n] = f2bf(acc[mt][nt][rg] + qkv_b[f]);
          }
        }
      }
    }
    __syncthreads();

    // attention: wave 0 -> head hp*2, wave 1 -> head hp*2+1
    if (wave < 2 && lane < 49) {
      const int head = hp * 2 + wave;
      float q[32];
#pragma unroll
      for (int kk = 0; kk < 4; ++kk)
        unpack8(*(uint4*)&qkvs[lane * 192 + wave * 32 + kk * 8], q + kk * 8);
#pragma unroll
      for (int k = 0; k < 32; ++k) q[k] *= 0.17677669529663689f;   // HD^-0.5

      const int i1 = lane / 7, j1 = lane - (lane / 7) * 7;
      const int rid1 = region3(wwh * 7 + i1) * 3 + region3(www * 7 + j1);

      float mx = -3.0e38f, den = 0.f, o[32];
#pragma unroll
      for (int k = 0; k < 32; ++k) o[k] = 0.f;

      for (int m = 0; m < 49; ++m) {
        float kv[32];
#pragma unroll
        for (int kk = 0; kk < 4; ++kk)
          unpack8(*(uint4*)&qkvs[m * 192 + 64 + wave * 32 + kk * 8], kv + kk * 8);
        float d = 0.f;
#pragma unroll
        for (int k = 0; k < 32; ++k) d += q[k] * kv[k];
        int i2 = m / 7, j2 = m - (m / 7) * 7;
        d += btab[((i1 - i2 + 6) * 13 + (j1 - j2 + 6)) * 12 + head];
        if (region3(wwh * 7 + i2) * 3 + region3(www * 7 + j2) != rid1) d -= 100.f;
        float nm = fmaxf(mx, d);
        float sc = __expf(mx - nm);
        float p  = __expf(d - nm);
        den = den * sc + p;
        float vv[32];
#pragma unroll
        for (int kk = 0; kk < 4; ++kk)
          unpack8(*(uint4*)&qkvs[m * 192 + 128 + wave * 32 + kk * 8], vv + kk * 8);
#pragma unroll
        for (int k = 0; k < 32; ++k) o[k] = o[k] * sc + p * vv[k];
        mx = nm;
      }
      float inv = 1.f / den;
      int h  = wwh * 7 + i1 + 3; if (h  >= 28) h  -= 28;
      int w2 = www * 7 + j1 + 3; if (w2 >= 28) w2 -= 28;
      float* orow = out + ((size_t)(bimg * 784 + h * 28 + w2)) * 384 + head * 32;
#pragma unroll
      for (int k = 0; k < 8; ++k) {
        float4 f4 = make_float4(o[4*k] * inv, o[4*k+1] * inv, o[4*k+2] * inv, o[4*k+3] * inv);
        *(float4*)&orow[4 * k] = f4;
      }
    }
    __syncthreads();
  }
}

// ---------------------------------------------------------------------------
// K2: proj + residual(x), in-place on d_out (fp32). Block owns 64 rows x all
// 384 cols; stages own rows (fp32 -> bf16 LDS), then overwrites. Race-free.
// ---------------------------------------------------------------------------
__global__ __launch_bounds__(256) void proj_kernel(
    const float* attn, const float* __restrict__ proj_w, const float* __restrict__ proj_b,
    const float* __restrict__ x, float* outp)
{
  __shared__ __align__(16) u16 As[64 * 392];
  const int tid  = threadIdx.x;
  const int lane = tid & 63;
  const int wave = tid >> 6;
  const int quad = lane >> 4;
  const int r16  = lane & 15;
  const int bm   = blockIdx.x * 64;

  for (int e = tid * 8; e < 64 * 384; e += 2048) {
    int r = e / 384, c = e - (e / 384) * 384;
    *(uint4*)&As[r * 392 + c] = pack8f(attn + (size_t)(bm + r) * 384 + c);
  }
  __syncthreads();

  f32x4 acc[4][6];
#pragma unroll
  for (int a = 0; a < 4; ++a)
#pragma unroll
    for (int c = 0; c < 6; ++c) acc[a][c] = (f32x4){0.f, 0.f, 0.f, 0.f};

  for (int k0 = 0; k0 < 384; k0 += 32) {
    bf16x8 af[4];
#pragma unroll
    for (int mt = 0; mt < 4; ++mt)
      af[mt] = *(const bf16x8*)&As[(mt * 16 + r16) * 392 + k0 + quad * 8];
#pragma unroll
    for (int nt = 0; nt < 6; ++nt) {
      int n = wave * 96 + nt * 16 + r16;
      bf16x8 bf = ldw8(proj_w + (size_t)n * 384 + k0 + quad * 8);
#pragma unroll
      for (int mt = 0; mt < 4; ++mt)
        acc[mt][nt] = __builtin_amdgcn_mfma_f32_16x16x32_bf16(af[mt], bf, acc[mt][nt], 0, 0, 0);
    }
  }
#pragma unroll
  for (int mt = 0; mt < 4; ++mt) {
#pragma unroll
    for (int nt = 0; nt < 6; ++nt) {
#pragma unroll
      for (int rg = 0; rg < 4; ++rg) {
        int gm = bm + mt * 16 + quad * 4 + rg;
        int gn = wave * 96 + nt * 16 + r16;
        float v = acc[mt][nt][rg] + proj_b[gn] + x[(size_t)gm * 384 + gn];
        outp[(size_t)gm * 384 + gn] = v;
      }
    }
  }
}

// ---------------------------------------------------------------------------
// K3: fused LN2 + FC1 + GELU + FC2 + residual, in-place on d_out (fp32).
// Block owns 32 rows; hidden tile 32x1536 bf16 in LDS (~124 KB total LDS).
// ---------------------------------------------------------------------------
__global__ __launch_bounds__(256) void mlp_kernel(
    const float* __restrict__ n2w, const float* __restrict__ n2b,
    const float* __restrict__ fc1_w, const float* __restrict__ fc1_b,
    const float* __restrict__ fc2_w, const float* __restrict__ fc2_b,
    float* xr)
{
  __shared__ __align__(16) u16 xs[32 * 392];
  __shared__ __align__(16) u16 hs[32 * 1544];
  __shared__ float mustd[64];
  const int tid  = threadIdx.x;
  const int lane = tid & 63;
  const int wave = tid >> 6;
  const int quad = lane >> 4;
  const int r16  = lane & 15;
  const int bm   = blockIdx.x * 32;

  for (int e = tid * 8; e < 32 * 384; e += 2048) {
    int r = e / 384, c = e - (e / 384) * 384;
    *(uint4*)&xs[r * 392 + c] = pack8f(xr + (size_t)(bm + r) * 384 + c);
  }
  __syncthreads();

  for (int r = wave; r < 32; r += 4) {
    float v[6]; float s = 0.f;
#pragma unroll
    for (int k = 0; k < 6; ++k) { v[k] = bf2f(xs[r * 392 + lane + k * 64]); s += v[k]; }
#pragma unroll
    for (int off = 32; off; off >>= 1) s += __shfl_xor(s, off);
    float mu = s * (1.f / 384.f);
    float vs = 0.f;
#pragma unroll
    for (int k = 0; k < 6; ++k) { float d = v[k] - mu; vs += d * d; }
#pragma unroll
    for (int off = 32; off; off >>= 1) vs += __shfl_xor(vs, off);
    if (lane == 0) { mustd[r] = mu; mustd[32 + r] = rsqrtf(vs * (1.f / 384.f) + 1e-5f); }
  }
  __syncthreads();

  for (int e = tid * 8; e < 32 * 384; e += 2048) {
    int r = e / 384, c = e - (e / 384) * 384;
    float mu = mustd[r], rs = mustd[32 + r];
    float v[8];
    unpack8(*(uint4*)&xs[r * 392 + c], v);
    float4 w0 = *(const float4*)(n2w + c), w1 = *(const float4*)(n2w + c + 4);
    float4 b0 = *(const float4*)(n2b + c), b1 = *(const float4*)(n2b + c + 4);
    float wv[8] = {w0.x, w0.y, w0.z, w0.w, w1.x, w1.y, w1.z, w1.w};
    float bv[8] = {b0.x, b0.y, b0.z, b0.w, b1.x, b1.y, b1.z, b1.w};
    unsigned pk[4];
#pragma unroll
    for (int i = 0; i < 4; ++i) {
      u16 a = f2bf((v[2*i]   - mu) * rs * wv[2*i]   + bv[2*i]);
      u16 b = f2bf((v[2*i+1] - mu) * rs * wv[2*i+1] + bv[2*i+1]);
      pk[i] = (unsigned)a | ((unsigned)b << 16);
    }
    *(uint4*)&xs[r * 392 + c] = make_uint4(pk[0], pk[1], pk[2], pk[3]);
  }
  __syncthreads();

  // FC1 + GELU -> hs, 4 passes of 384 cols
  for (int nb = 0; nb < 4; ++nb) {
    f32x4 acc[2][6];
#pragma unroll
    for (int a = 0; a < 2; ++a)
#pragma unroll
      for (int c = 0; c < 6; ++c) acc[a][c] = (f32x4){0.f, 0.f, 0.f, 0.f};
    for (int k0 = 0; k0 < 384; k0 += 32) {
      bf16x8 af[2];
#pragma unroll
      for (int mt = 0; mt < 2; ++mt)
        af[mt] = *(const bf16x8*)&xs[(mt * 16 + r16) * 392 + k0 + quad * 8];
#pragma unroll
      for (int nt = 0; nt < 6; ++nt) {
        int ng = nb * 384 + wave * 96 + nt * 16 + r16;
        bf16x8 bf = ldw8(fc1_w + (size_t)ng * 384 + k0 + quad * 8);
#pragma unroll
        for (int mt = 0; mt < 2; ++mt)
          acc[mt][nt] = __builtin_amdgcn_mfma_f32_16x16x32_bf16(af[mt], bf, acc[mt][nt], 0, 0, 0);
      }
    }
#pragma unroll
    for (int mt = 0; mt < 2; ++mt) {
#pragma unroll
      for (int nt = 0; nt < 6; ++nt) {
#pragma unroll
        for (int rg = 0; rg < 4; ++rg) {
          int row = mt * 16 + quad * 4 + rg;
          int nl  = nb * 384 + wave * 96 + nt * 16 + r16;
          float v = acc[mt][nt][rg] + fc1_b[nl];
          v = 0.5f * v * (1.0f + erff(v * 0.70710678118654752f));
          hs[row * 1544 + nl] = f2bf(v);
        }
      }
    }
  }
  __syncthreads();

  // FC2 + residual (in-place, fp32)
  f32x4 acc[2][6];
#pragma unroll
  for (int a = 0; a < 2; ++a)
#pragma unroll
    for (int c = 0; c < 6; ++c) acc[a][c] = (f32x4){0.f, 0.f, 0.f, 0.f};
  for (int k0 = 0; k0 < 1536; k0 += 32) {
    bf16x8 af[2];
#pragma unroll
    for (int mt = 0; mt < 2; ++mt)
      af[mt] = *(const bf16x8*)&hs[(mt * 16 + r16) * 1544 + k0 + quad * 8];
#pragma unroll
    for (int nt = 0; nt < 6; ++nt) {
      int n = wave * 96 + nt * 16 + r16;
      bf16x8 bf = ldw8(fc2_w + (size_t)n * 1536 + k0 + quad * 8);
#pragma unroll
      for (int mt = 0; mt < 2; ++mt)
        acc[mt][nt] = __builtin_amdgcn_mfma_f32_16x16x32_bf16(af[mt], bf, acc[mt][nt], 0, 0, 0);
    }
  }
#pragma unroll
  for (int mt = 0; mt < 2; ++mt) {
#pragma unroll
    for (int nt = 0; nt < 6; ++nt) {
#pragma unroll
      for (int rg = 0; rg < 4; ++rg) {
        int gm = bm + mt * 16 + quad * 4 + rg;
        int gn = wave * 96 + nt * 16 + r16;
        size_t g = (size_t)gm * 384 + gn;
        xr[g] = acc[mt][nt][rg] + fc2_b[gn] + xr[g];
      }
    }
  }
}

// ---------------------------------------------------------------------------
extern "C" void kernel_launch(void* const* d_in, const int* in_sizes, int n_in,
                              void* d_out, int out_size, void* d_ws, size_t ws_size,
                              hipStream_t stream) {
  const float* x      = (const float*)d_in[0];
  const float* n1w    = (const float*)d_in[1];
  const float* n1b    = (const float*)d_in[2];
  const float* qkv_w  = (const float*)d_in[3];
  const float* qkv_b  = (const float*)d_in[4];
  const float* proj_w = (const float*)d_in[5];
  const float* proj_b = (const float*)d_in[6];
  const float* btab   = (const float*)d_in[7];
  const float* n2w    = (const float*)d_in[8];
  const float* n2b    = (const float*)d_in[9];
  const float* fc1_w  = (const float*)d_in[10];
  const float* fc1_b  = (const float*)d_in[11];
  const float* fc2_w  = (const float*)d_in[12];
  const float* fc2_b  = (const float*)d_in[13];

  float* dout = (float*)d_out;
  (void)d_ws; (void)ws_size; (void)in_sizes; (void)n_in; (void)out_size;

  // K1: fused LN1+shift+QKV+attention -> attn_out (fp32, pixel order)
  win_attn_kernel<<<1024, 256, 0, stream>>>(x, n1w, n1b, qkv_w, qkv_b, btab, dout);
  // K2: proj + residual(x), in place -> xr
  proj_kernel<<<784, 256, 0, stream>>>(dout, proj_w, proj_b, x, dout);
  // K3: fused LN2+FC1+GELU+FC2+residual, in place -> final output
  mlp_kernel<<<1568, 256, 0, stream>>>(n2w, n2b, fc1_w, fc1_b, fc2_w, fc2_b, dout);
}